// Round 7
// baseline (595.570 us; speedup 1.0000x reference)
//
#include <hip/hip_runtime.h>
#include <hip/hip_bf16.h>
#include <math.h>

typedef __bf16 bf16x8 __attribute__((ext_vector_type(8)));
typedef float f32x4 __attribute__((ext_vector_type(4)));
typedef unsigned int u32x2 __attribute__((ext_vector_type(2)));

__device__ __forceinline__ f32x4 mfma16(bf16x8 a, bf16x8 b, f32x4 c) {
  return __builtin_amdgcn_mfma_f32_16x16x32_bf16(a, b, c, 0, 0, 0);
}

__device__ __forceinline__ float gelu_f(float v) {
  return 0.5f * v * (1.0f + erff(v * 0.70710678118654752f));
}

__device__ __forceinline__ void async16(const void* g, void* l) {
  __builtin_amdgcn_global_load_lds((const __attribute__((address_space(1))) unsigned int*)g,
                                   (__attribute__((address_space(3))) unsigned int*)l, 16, 0, 0);
}

__device__ __forceinline__ unsigned lds_off(const void* p) {
  return (unsigned)(unsigned long long)(const __attribute__((address_space(3))) void*)p;
}

// ---- weight convert + transpose: Wt[n][k] = (bf16) W[k][n];  W is K x N row-major
__global__ void wprep_kernel(const float* __restrict__ W, __bf16* __restrict__ Wt, int K, int N) {
  long i = (long)blockIdx.x * 256 + threadIdx.x;
  if (i >= (long)K * N) return;
  int k = (int)(i % K), n = (int)(i / K);
  Wt[i] = (__bf16)W[(long)k * N + n];
}

__global__ void wprep_qkv_kernel(const float* __restrict__ Wq, const float* __restrict__ Wk,
                                 const float* __restrict__ Wv, __bf16* __restrict__ Wt) {
  long i = (long)blockIdx.x * 256 + threadIdx.x;
  if (i >= 2304L * 768) return;
  int k = (int)(i % 768), n = (int)(i / 768);
  const float* W = (n < 768) ? Wq : (n < 1536) ? Wk : Wv;
  Wt[i] = (__bf16)W[(long)k * 768 + (n % 768)];
}

__global__ void bias_cat_kernel(const float* __restrict__ bq, const float* __restrict__ bk,
                                const float* __restrict__ bv, float* __restrict__ o) {
  int i = blockIdx.x * 256 + threadIdx.x;
  if (i >= 2304) return;
  o[i] = (i < 768) ? bq[i] : (i < 1536) ? bk[i - 768] : bv[i - 1536];
}

// ---- layernorm: fp32 in (rows x 768), bf16 out. One block (256 thr) per row.
__global__ __launch_bounds__(256) void ln_kernel(const float* __restrict__ x, const float* __restrict__ g,
                                                 const float* __restrict__ b, __bf16* __restrict__ out) {
  int row = blockIdx.x;
  const float* xr = x + (long)row * 768;
  float v0 = xr[threadIdx.x], v1 = xr[threadIdx.x + 256], v2 = xr[threadIdx.x + 512];
  float s = v0 + v1 + v2, s2 = v0 * v0 + v1 * v1 + v2 * v2;
#pragma unroll
  for (int m = 1; m < 64; m <<= 1) { s += __shfl_xor(s, m); s2 += __shfl_xor(s2, m); }
  __shared__ float ws1[4], ws2[4];
  int wv = threadIdx.x >> 6;
  if ((threadIdx.x & 63) == 0) { ws1[wv] = s; ws2[wv] = s2; }
  __syncthreads();
  s = ws1[0] + ws1[1] + ws1[2] + ws1[3];
  s2 = ws2[0] + ws2[1] + ws2[2] + ws2[3];
  float mu = s * (1.0f / 768.0f);
  float var = s2 * (1.0f / 768.0f) - mu * mu;
  float rstd = rsqrtf(var + 1e-5f);
  __bf16* orow = out + (long)row * 768;
  orow[threadIdx.x]       = (__bf16)((v0 - mu) * rstd * g[threadIdx.x]       + b[threadIdx.x]);
  orow[threadIdx.x + 256] = (__bf16)((v1 - mu) * rstd * g[threadIdx.x + 256] + b[threadIdx.x + 256]);
  orow[threadIdx.x + 512] = (__bf16)((v2 - mu) * rstd * g[threadIdx.x + 512] + b[threadIdx.x + 512]);
}

// ---- GEMM: 256x256 tile, BK=64, 8 waves (2M x 4N, wave tile 128x64), 8-phase schedule:
// A fragments front-loaded Ph1-2 (A LDS dead after Ph2 -> restaged Ph3-4), B consumed per-kk.
// Stage stream: Ph1-2 B(t1), Ph3-4 A(t2), Ph5-6 B(t2), Ph7-8 A(t3); vmcnt(4) at Ph4/Ph8 end.
// T2 xor-swizzle (pre-swizzled global src, XOR on read). Bijective XCD swizzle on (bx,by).
// C[M,N] = epi(A[M,K] @ Wt[N,K]^T + bias). M%256==0, N%256==0, K%128==0.
template <int EPI>
__global__ __launch_bounds__(512, 2) void gemm_kernel(const __bf16* __restrict__ A, const __bf16* __restrict__ Wt,
                                                      const float* __restrict__ bias, const float* __restrict__ res,
                                                      float* __restrict__ outf, __bf16* __restrict__ outb,
                                                      int M, int N, int K) {
  __shared__ __align__(16) __bf16 Asb[2][16384];   // 256x64 per buf
  __shared__ __align__(16) __bf16 Bsb[2][16384];   // 256x64 per buf
  const int tid = threadIdx.x, lane = tid & 63, w = tid >> 6;
  const int wm = w >> 2, wn = w & 3, lr = lane & 15, lh = lane >> 4;
  // XCD swizzle: 8 consecutive m-panels per XCD (bijective for any gridDim.x, gridDim.y=64)
  const int gx = gridDim.x;
  int id = blockIdx.x + gx * blockIdx.y;
  int xcd = id & 7, slot = id >> 3;
  int by = xcd * 8 + slot / gx;
  int bx = slot % gx;
  const int m0 = by * 256, n0 = bx * 256;
  const int nt = K >> 6;
  int srow[4], scol[4];
#pragma unroll
  for (int l = 0; l < 4; ++l) {
    int c = l * 512 + tid;
    srow[l] = c >> 3;
    scol[l] = ((c & 7) ^ ((c >> 3) & 7)) * 8;
  }
  const __bf16* Ag = A + (long)m0 * K;
  const __bf16* Bg = Wt + (long)n0 * K;
  const int ldst = w * 512;

#define SA(buf, t, l) async16(Ag + (long)srow[l] * K + ((t) << 6) + scol[l], &Asb[buf][(l)*4096 + ldst])
#define SB(buf, t, l) async16(Bg + (long)srow[l] * K + ((t) << 6) + scol[l], &Bsb[buf][(l)*4096 + ldst])
#define BAR __builtin_amdgcn_s_barrier()
#define LGKM0 { asm volatile("s_waitcnt lgkmcnt(0)" ::: "memory"); __builtin_amdgcn_sched_barrier(0); }
#define VM4 asm volatile("s_waitcnt vmcnt(4)" ::: "memory")

#define RDA(dst, As, kk)                                                            \
  _Pragma("unroll") for (int m4 = 0; m4 < 8; ++m4) {                                \
    int row = wm * 128 + m4 * 16 + lr;                                              \
    dst[m4] = *(const bf16x8*)&(As)[row * 64 + (((kk)*32 + lh * 8) ^ ((row & 7) << 3))]; \
  }
#define RDB(dst, Bs, kk, n)                                                         \
  {                                                                                 \
    int row = wn * 64 + (n)*16 + lr;                                                \
    dst = *(const bf16x8*)&(Bs)[row * 64 + (((kk)*32 + lh * 8) ^ ((row & 7) << 3))]; \
  }
#define MM(af, b0_, b1_, n_lo)                                                      \
  __builtin_amdgcn_s_setprio(1);                                                    \
  _Pragma("unroll") for (int m = 0; m < 8; ++m) {                                   \
    acc[m][n_lo] = mfma16(af[m], b0_, acc[m][n_lo]);                                \
    acc[m][n_lo + 1] = mfma16(af[m], b1_, acc[m][n_lo + 1]);                        \
  }                                                                                 \
  __builtin_amdgcn_s_setprio(0);

  f32x4 acc[8][4] = {};
  // prologue: A(t0), B(t0), A(t1) staged; B(t1) staged in Ph1-2 of iteration 0
#pragma unroll
  for (int l = 0; l < 4; ++l) SA(0, 0, l);
#pragma unroll
  for (int l = 0; l < 4; ++l) SB(0, 0, l);
#pragma unroll
  for (int l = 0; l < 4; ++l) SA(1, 1, l);
  VM4;
  BAR;

  const int half = nt >> 1;
  for (int i = 0; i < half; ++i) {
    const int t1 = 2 * i + 1;
    const int t2 = (2 * i + 2 < nt) ? 2 * i + 2 : 0;   // dummy re-stage on tail
    const int t3 = (2 * i + 3 < nt) ? 2 * i + 3 : 1;
    bf16x8 a0[8], a1[8], b0, b1, b2, b3;
    {
      const __bf16* As = Asb[0];
      const __bf16* Bs = Bsb[0];
      // Ph1: read A(kk0) + B(kk0,n0-1); stage B-t1[0,1]; mfma kk0 n0-1
      RDA(a0, As, 0); RDB(b0, Bs, 0, 0); RDB(b1, Bs, 0, 1);
      SB(1, t1, 0); SB(1, t1, 1);
      BAR; LGKM0; MM(a0, b0, b1, 0); BAR;
      // Ph2: read A(kk1) + B(kk0,n2-3); stage B-t1[2,3]; mfma kk0 n2-3
      RDA(a1, As, 1); RDB(b2, Bs, 0, 2); RDB(b3, Bs, 0, 3);
      SB(1, t1, 2); SB(1, t1, 3);
      BAR; LGKM0; MM(a0, b2, b3, 2); BAR;
      // Ph3: read B(kk1,n0-1); stage A-t2[0,1]; mfma kk1 n0-1
      RDB(b0, Bs, 1, 0); RDB(b1, Bs, 1, 1);
      SA(0, t2, 0); SA(0, t2, 1);
      BAR; LGKM0; MM(a1, b0, b1, 0); BAR;
      // Ph4: read B(kk1,n2-3); stage A-t2[2,3]; mfma kk1 n2-3; vmcnt(4)
      RDB(b2, Bs, 1, 2); RDB(b3, Bs, 1, 3);
      SA(0, t2, 2); SA(0, t2, 3);
      BAR; LGKM0; MM(a1, b2, b3, 2); VM4; BAR;
    }
    {
      const __bf16* As = Asb[1];
      const __bf16* Bs = Bsb[1];
      // Ph5
      RDA(a0, As, 0); RDB(b0, Bs, 0, 0); RDB(b1, Bs, 0, 1);
      SB(0, t2, 0); SB(0, t2, 1);
      BAR; LGKM0; MM(a0, b0, b1, 0); BAR;
      // Ph6
      RDA(a1, As, 1); RDB(b2, Bs, 0, 2); RDB(b3, Bs, 0, 3);
      SB(0, t2, 2); SB(0, t2, 3);
      BAR; LGKM0; MM(a0, b2, b3, 2); BAR;
      // Ph7
      RDB(b0, Bs, 1, 0); RDB(b1, Bs, 1, 1);
      SA(1, t3, 0); SA(1, t3, 1);
      BAR; LGKM0; MM(a1, b0, b1, 0); BAR;
      // Ph8
      RDB(b2, Bs, 1, 2); RDB(b3, Bs, 1, 3);
      SA(1, t3, 2); SA(1, t3, 3);
      BAR; LGKM0; MM(a1, b2, b3, 2); VM4; BAR;
    }
  }
#undef SA
#undef SB
#undef RDA
#undef RDB
#undef MM

#pragma unroll
  for (int m = 0; m < 8; ++m)
#pragma unroll
    for (int n = 0; n < 4; ++n) {
      int col = n0 + wn * 64 + n * 16 + lr;
      float bc = bias[col];
#pragma unroll
      for (int j = 0; j < 4; ++j) {
        int row = m0 + wm * 128 + m * 16 + lh * 4 + j;
        float v = acc[m][n][j] + bc;
        if (EPI == 1) v = gelu_f(v);
        if (EPI == 2) outf[(long)row * N + col] = v + res[(long)row * N + col];
        else          outb[(long)row * N + col] = (__bf16)v;
      }
    }
}

// ---- flash attention on fused qkv buffer (rows x 2304). (unchanged from R6)
__global__ __launch_bounds__(256) void attn_kernel(const __bf16* __restrict__ qkv, __bf16* __restrict__ o) {
  __shared__ __bf16 K_lds[64][72];
  __shared__ __align__(16) unsigned char Vt[8448];
  __shared__ __bf16 P_lds[4][32][72];
  const int tid = threadIdx.x;
  const int lane = tid & 63, wv = tid >> 6;
  const int lr = lane & 15, lh = lane >> 4;
  const int hb = blockIdx.x, qt = blockIdx.y;
  const int h = hb % 12, bz = hb / 12;
  const int qrow0 = bz * 1024 + qt * 128 + wv * 32;
  const int hcol = h * 64;
  const __bf16* q = qkv + hcol;
  const __bf16* k = qkv + 768 + hcol;
  const __bf16* v = qkv + 1536 + hcol;
  const float QSC = 0.18033688011112042f;  // 0.125 * log2(e)
  bf16x8 aq[2][2];
#pragma unroll
  for (int r = 0; r < 2; ++r)
#pragma unroll
    for (int kk = 0; kk < 2; ++kk) {
      bf16x8 t = *(const bf16x8*)(q + (long)(qrow0 + r * 16 + lr) * 2304 + kk * 32 + lh * 8);
#pragma unroll
      for (int e = 0; e < 8; ++e) t[e] = (__bf16)((float)t[e] * QSC);
      aq[r][kk] = t;
    }
  bf16x8 ones;
#pragma unroll
  for (int e = 0; e < 8; ++e) ones[e] = (__bf16)1.0f;
  f32x4 o_fr[2][4] = {};
  float m_s[2][4], l_s[2][4];
#pragma unroll
  for (int r = 0; r < 2; ++r)
#pragma unroll
    for (int j = 0; j < 4; ++j) { m_s[r][j] = 0.0f; l_s[r][j] = 0.0f; }
  const int r0 = tid >> 3, c0 = (tid & 7) * 8;
  const unsigned vt0 = lds_off(Vt) + (lane >> 4) * 1056 + (lane & 15) * 2;
  const int Tst = (r0 >> 2) * 4 + (c0 >> 4);
  const int vb = Tst * 128 + (r0 & 3) * 32 + (c0 & 15) * 2 + (Tst >> 3) * 32;

  bf16x8 rK[2], rV[2];
#pragma unroll
  for (int p = 0; p < 2; ++p) {
    long gr = (long)(bz * 1024 + p * 32 + r0) * 2304 + c0;
    rK[p] = *(const bf16x8*)(k + gr);
    rV[p] = *(const bf16x8*)(v + gr);
  }
#pragma unroll
  for (int p = 0; p < 2; ++p) {
    *(bf16x8*)&K_lds[p * 32 + r0][c0] = rK[p];
    *(bf16x8*)(Vt + vb + p * 4224) = rV[p];
  }
  __syncthreads();

  for (int t = 0; t < 16; ++t) {
    bf16x8 bk[4][2];
#pragma unroll
    for (int n = 0; n < 4; ++n)
#pragma unroll
      for (int kk = 0; kk < 2; ++kk)
        bk[n][kk] = *(const bf16x8*)&K_lds[n * 16 + lr][kk * 32 + lh * 8];
    if (t < 15) {
#pragma unroll
      for (int p = 0; p < 2; ++p) {
        long gr = (long)(bz * 1024 + (t + 1) * 64 + p * 32 + r0) * 2304 + c0;
        rK[p] = *(const bf16x8*)(k + gr);
        rV[p] = *(const bf16x8*)(v + gr);
      }
    }
    f32x4 sf[2][4];
    __builtin_amdgcn_s_setprio(1);
#pragma unroll
    for (int r = 0; r < 2; ++r)
#pragma unroll
      for (int n = 0; n < 4; ++n) {
        f32x4 s = {0.f, 0.f, 0.f, 0.f};
        s = mfma16(aq[r][0], bk[n][0], s);
        s = mfma16(aq[r][1], bk[n][1], s);
        sf[r][n] = s;
      }
    __builtin_amdgcn_s_setprio(0);
    float pp[2][4][4];
    bool ok = true;
#pragma unroll
    for (int r = 0; r < 2; ++r)
#pragma unroll
      for (int j = 0; j < 4; ++j) {
        float lm = fmaxf(fmaxf(sf[r][0][j], sf[r][1][j]), fmaxf(sf[r][2][j], sf[r][3][j]));
        ok = ok && (lm <= m_s[r][j] + 11.54f);
      }
    if (!__all(ok)) {
#pragma unroll
      for (int r = 0; r < 2; ++r) {
        float rmax[4];
#pragma unroll
        for (int j = 0; j < 4; ++j)
          rmax[j] = fmaxf(fmaxf(sf[r][0][j], sf[r][1][j]), fmaxf(sf[r][2][j], sf[r][3][j]));
#pragma unroll
        for (int m = 1; m < 16; m <<= 1)
#pragma unroll
          for (int j = 0; j < 4; ++j) rmax[j] = fmaxf(rmax[j], __shfl_xor(rmax[j], m));
#pragma unroll
        for (int j = 0; j < 4; ++j) {
          float nm = fmaxf(m_s[r][j], rmax[j]);
          float corr = __builtin_amdgcn_exp2f(m_s[r][j] - nm);
          m_s[r][j] = nm;
          l_s[r][j] *= corr;
#pragma unroll
          for (int d = 0; d < 4; ++d) o_fr[r][d][j] *= corr;
        }
      }
    }
#pragma unroll
    for (int r = 0; r < 2; ++r)
#pragma unroll
      for (int n = 0; n < 4; ++n)
#pragma unroll
        for (int j = 0; j < 4; ++j)
          pp[r][n][j] = __builtin_amdgcn_exp2f(sf[r][n][j] - m_s[r][j]);
#pragma unroll
    for (int r = 0; r < 2; ++r)
#pragma unroll
      for (int n = 0; n < 4; ++n)
#pragma unroll
        for (int j = 0; j < 4; ++j)
          P_lds[wv][r * 16 + lh * 4 + j][n * 16 + lr] = (__bf16)pp[r][n][j];
    u32x2 trv[4][2][2];
#pragma unroll
    for (int d0 = 0; d0 < 4; ++d0)
#pragma unroll
      for (int ks = 0; ks < 2; ++ks) {
        unsigned a = vt0 + ks * 4224 + d0 * 128;
        asm volatile("ds_read_b64_tr_b16 %0, %1" : "=v"(trv[d0][ks][0]) : "v"(a));
        asm volatile("ds_read_b64_tr_b16 %0, %1 offset:512" : "=v"(trv[d0][ks][1]) : "v"(a));
      }
    bf16x8 ap[2][2];
#pragma unroll
    for (int r = 0; r < 2; ++r)
#pragma unroll
      for (int ks = 0; ks < 2; ++ks)
        ap[r][ks] = *(const bf16x8*)&P_lds[wv][r * 16 + lr][ks * 32 + lh * 8];
    asm volatile("s_waitcnt lgkmcnt(0)");
    __builtin_amdgcn_sched_barrier(0);
    __builtin_amdgcn_s_setprio(1);
#pragma unroll
    for (int r = 0; r < 2; ++r) {
      f32x4 ls = {0.f, 0.f, 0.f, 0.f};
      ls = mfma16(ap[r][0], ones, ls);
      ls = mfma16(ap[r][1], ones, ls);
#pragma unroll
      for (int j = 0; j < 4; ++j) l_s[r][j] += ls[j];
    }
#pragma unroll
    for (int d0 = 0; d0 < 4; ++d0) {
      union { u32x2 u[2]; bf16x8 v8; } b0, b1;
      b0.u[0] = trv[d0][0][0]; b0.u[1] = trv[d0][0][1];
      b1.u[0] = trv[d0][1][0]; b1.u[1] = trv[d0][1][1];
#pragma unroll
      for (int r = 0; r < 2; ++r) {
        o_fr[r][d0] = mfma16(ap[r][0], b0.v8, o_fr[r][d0]);
        o_fr[r][d0] = mfma16(ap[r][1], b1.v8, o_fr[r][d0]);
      }
    }
    __builtin_amdgcn_s_setprio(0);
    __syncthreads();
    if (t < 15) {
#pragma unroll
      for (int p = 0; p < 2; ++p) {
        *(bf16x8*)&K_lds[p * 32 + r0][c0] = rK[p];
        *(bf16x8*)(Vt + vb + p * 4224) = rV[p];
      }
      __syncthreads();
    }
  }
#pragma unroll
  for (int r = 0; r < 2; ++r)
#pragma unroll
    for (int d = 0; d < 4; ++d)
#pragma unroll
      for (int j = 0; j < 4; ++j) {
        int row = qrow0 + r * 16 + lh * 4 + j;
        int col = hcol + d * 16 + lr;
        o[(long)row * 768 + col] = (__bf16)(o_fr[r][d][j] * (1.0f / l_s[r][j]));
      }
}

extern "C" void kernel_launch(void* const* d_in, const int* in_sizes, int n_in,
                              void* d_out, int out_size, void* d_ws, size_t ws_size,
                              hipStream_t stream) {
  const float* x    = (const float*)d_in[0];
  const float* ln1g = (const float*)d_in[1];
  const float* ln1b = (const float*)d_in[2];
  const float* wq   = (const float*)d_in[3];
  const float* bq   = (const float*)d_in[4];
  const float* wk   = (const float*)d_in[5];
  const float* bk   = (const float*)d_in[6];
  const float* wv   = (const float*)d_in[7];
  const float* bv   = (const float*)d_in[8];
  const float* wo   = (const float*)d_in[9];
  const float* bo   = (const float*)d_in[10];
  const float* ln2g = (const float*)d_in[11];
  const float* ln2b = (const float*)d_in[12];
  const float* w1   = (const float*)d_in[13];
  const float* b1   = (const float*)d_in[14];
  const float* w2   = (const float*)d_in[15];
  const float* b2   = (const float*)d_in[16];
  float* out = (float*)d_out;
  char* ws = (char*)d_ws;

  const long SD = 16384L * 768;
  const long SF = 16384L * 3072;

  __bf16* qkv = (__bf16*)(ws);                      // 16384 x 2304
  __bf16* f1  = (__bf16*)(ws);                      // aliases qkv (dead by FFN1)
  __bf16* hb  = (__bf16*)(ws + 2 * SF);             // LN1 out; later attn out
  float*  x2  = (float*)(ws + 2 * SF + 2 * SD);
  __bf16* h2  = (__bf16*)(ws + 2 * SF + 2 * SD + 4 * SD);
  __bf16* wtqkv = (__bf16*)(ws + 2 * SF + 2 * SD + 4 * SD + 2 * SD);  // 2304 x 768
  __bf16* wto = wtqkv + 2304L * 768;
  __bf16* wt1 = wto + 768L * 768;
  __bf16* wt2 = wt1 + 768L * 3072;
  float*  bqkv = (float*)(wt2 + 3072L * 768);

  wprep_qkv_kernel<<<(2304 * 768 + 255) / 256, 256, 0, stream>>>(wq, wk, wv, wtqkv);
  wprep_kernel<<<(768 * 768 + 255) / 256, 256, 0, stream>>>(wo, wto, 768, 768);
  wprep_kernel<<<(768 * 3072 + 255) / 256, 256, 0, stream>>>(w1, wt1, 768, 3072);
  wprep_kernel<<<(768 * 3072 + 255) / 256, 256, 0, stream>>>(w2, wt2, 3072, 768);
  bias_cat_kernel<<<9, 256, 0, stream>>>(bq, bk, bv, bqkv);

  ln_kernel<<<16384, 256, 0, stream>>>(x, ln1g, ln1b, hb);
  gemm_kernel<0><<<dim3(9, 64), 512, 0, stream>>>(hb, wtqkv, bqkv, nullptr, nullptr, qkv, 16384, 2304, 768);
  attn_kernel<<<dim3(192, 8), 256, 0, stream>>>(qkv, hb);
  gemm_kernel<2><<<dim3(3, 64), 512, 0, stream>>>(hb, wto, bo, x, x2, nullptr, 16384, 768, 768);
  ln_kernel<<<16384, 256, 0, stream>>>(x2, ln2g, ln2b, h2);
  gemm_kernel<1><<<dim3(12, 64), 512, 0, stream>>>(h2, wt1, b1, nullptr, nullptr, f1, 16384, 3072, 768);
  gemm_kernel<2><<<dim3(3, 64), 512, 0, stream>>>(f1, wt2, b2, x2, out, nullptr, 16384, 768, 3072);
}

// Round 8
// 530.584 us; speedup vs baseline: 1.1225x; 1.1225x over previous
//
#include <hip/hip_runtime.h>
#include <hip/hip_bf16.h>
#include <math.h>

typedef __bf16 bf16x8 __attribute__((ext_vector_type(8)));
typedef float f32x4 __attribute__((ext_vector_type(4)));
typedef unsigned int u32x2 __attribute__((ext_vector_type(2)));

__device__ __forceinline__ f32x4 mfma16(bf16x8 a, bf16x8 b, f32x4 c) {
  return __builtin_amdgcn_mfma_f32_16x16x32_bf16(a, b, c, 0, 0, 0);
}

__device__ __forceinline__ float gelu_f(float v) {
  return 0.5f * v * (1.0f + erff(v * 0.70710678118654752f));
}

__device__ __forceinline__ void async16(const void* g, void* l) {
  __builtin_amdgcn_global_load_lds((const __attribute__((address_space(1))) unsigned int*)g,
                                   (__attribute__((address_space(3))) unsigned int*)l, 16, 0, 0);
}

__device__ __forceinline__ unsigned lds_off(const void* p) {
  return (unsigned)(unsigned long long)(const __attribute__((address_space(3))) void*)p;
}

// ---- weight convert + transpose: Wt[n][k] = (bf16) W[k][n];  W is K x N row-major
__global__ void wprep_kernel(const float* __restrict__ W, __bf16* __restrict__ Wt, int K, int N) {
  long i = (long)blockIdx.x * 256 + threadIdx.x;
  if (i >= (long)K * N) return;
  int k = (int)(i % K), n = (int)(i / K);
  Wt[i] = (__bf16)W[(long)k * N + n];
}

__global__ void wprep_qkv_kernel(const float* __restrict__ Wq, const float* __restrict__ Wk,
                                 const float* __restrict__ Wv, __bf16* __restrict__ Wt) {
  long i = (long)blockIdx.x * 256 + threadIdx.x;
  if (i >= 2304L * 768) return;
  int k = (int)(i % 768), n = (int)(i / 768);
  const float* W = (n < 768) ? Wq : (n < 1536) ? Wk : Wv;
  Wt[i] = (__bf16)W[(long)k * 768 + (n % 768)];
}

__global__ void bias_cat_kernel(const float* __restrict__ bq, const float* __restrict__ bk,
                                const float* __restrict__ bv, float* __restrict__ o) {
  int i = blockIdx.x * 256 + threadIdx.x;
  if (i >= 2304) return;
  o[i] = (i < 768) ? bq[i] : (i < 1536) ? bk[i - 768] : bv[i - 1536];
}

// ---- layernorm: fp32 in (rows x 768), bf16 out. One block (256 thr) per row.
__global__ __launch_bounds__(256) void ln_kernel(const float* __restrict__ x, const float* __restrict__ g,
                                                 const float* __restrict__ b, __bf16* __restrict__ out) {
  int row = blockIdx.x;
  const float* xr = x + (long)row * 768;
  float v0 = xr[threadIdx.x], v1 = xr[threadIdx.x + 256], v2 = xr[threadIdx.x + 512];
  float s = v0 + v1 + v2, s2 = v0 * v0 + v1 * v1 + v2 * v2;
#pragma unroll
  for (int m = 1; m < 64; m <<= 1) { s += __shfl_xor(s, m); s2 += __shfl_xor(s2, m); }
  __shared__ float ws1[4], ws2[4];
  int wv = threadIdx.x >> 6;
  if ((threadIdx.x & 63) == 0) { ws1[wv] = s; ws2[wv] = s2; }
  __syncthreads();
  s = ws1[0] + ws1[1] + ws1[2] + ws1[3];
  s2 = ws2[0] + ws2[1] + ws2[2] + ws2[3];
  float mu = s * (1.0f / 768.0f);
  float var = s2 * (1.0f / 768.0f) - mu * mu;
  float rstd = rsqrtf(var + 1e-5f);
  __bf16* orow = out + (long)row * 768;
  orow[threadIdx.x]       = (__bf16)((v0 - mu) * rstd * g[threadIdx.x]       + b[threadIdx.x]);
  orow[threadIdx.x + 256] = (__bf16)((v1 - mu) * rstd * g[threadIdx.x + 256] + b[threadIdx.x + 256]);
  orow[threadIdx.x + 512] = (__bf16)((v2 - mu) * rstd * g[threadIdx.x + 512] + b[threadIdx.x + 512]);
}

// ---- GEMM: 256x192 tile, BK=64, 8 waves (2M x 4N, wave tile 128x48), double-buffered LDS,
// REGISTER-PIPELINED: fragment ds_reads for half-tile X issued during MFMAs of half-tile X-1
// (compiler-counted lgkm waits); stage(t+2) issued mid-iteration, drained next iteration.
// T2 xor-swizzle (pre-swizzled global src, XOR on read); bijective XCD swizzle.
// C[M,N] = epi(A[M,K] @ Wt[N,K]^T + bias). M%256==0, N%192==0, K%64==0, K>=128.
template <int EPI>
__global__ __launch_bounds__(512, 2) void gemm_kernel(const __bf16* __restrict__ A, const __bf16* __restrict__ Wt,
                                                      const float* __restrict__ bias, const float* __restrict__ res,
                                                      float* __restrict__ outf, __bf16* __restrict__ outb,
                                                      int M, int N, int K) {
  __shared__ __align__(16) __bf16 Asb[2][16384];   // 256x64 per buf
  __shared__ __align__(16) __bf16 Bsb[2][12288];   // 192x64 per buf
  const int tid = threadIdx.x, lane = tid & 63, w = tid >> 6;
  const int wm = w >> 2, wn = w & 3, lr = lane & 15, lh = lane >> 4;
  // bijective XCD swizzle (gridDim.y = 64, 8 | 64): 8 consecutive m-panels per XCD
  const int gx = gridDim.x;
  int id = blockIdx.x + gx * blockIdx.y;
  int xcd = id & 7, slot = id >> 3;
  int by = xcd * 8 + slot / gx;
  int bx = slot % gx;
  const int m0 = by * 256, n0 = bx * 192;
  const int nt = K >> 6;
  int srow[4], scol[4];
#pragma unroll
  for (int l = 0; l < 4; ++l) {
    int c = l * 512 + tid;
    srow[l] = c >> 3;
    scol[l] = ((c & 7) ^ ((c >> 3) & 7)) * 8;
  }
  const __bf16* Ag = A + (long)m0 * K;
  const __bf16* Bg = Wt + (long)n0 * K;
  const int ldst = w * 512;

#define SA(buf, ts, l) async16(Ag + (long)srow[l] * K + ((ts) << 6) + scol[l], &Asb[buf][(l)*4096 + ldst])
#define SB(buf, ts, l) async16(Bg + (long)srow[l] * K + ((ts) << 6) + scol[l], &Bsb[buf][(l)*4096 + ldst])

  // fragment base offsets (elems). row&7 == lr&7 for all fragment rows -> single base
  // per (operand, kk); per-fragment delta is the compile-time m4*1024 / n*1024 immediate.
  const int xa = (lr & 7) << 3;
  const int aO0 = (wm * 128 + lr) * 64 + ((lh * 8) ^ xa);
  const int aO1 = (wm * 128 + lr) * 64 + ((32 + lh * 8) ^ xa);
  const int bO0 = (wn * 48 + lr) * 64 + ((lh * 8) ^ xa);
  const int bO1 = (wn * 48 + lr) * 64 + ((32 + lh * 8) ^ xa);

  f32x4 acc[8][3] = {};
  bf16x8 aA[8], bA[3], aB[8], bB[3];

  // prologue: stage tiles 0,1; read kk0(0)
#pragma unroll
  for (int l = 0; l < 4; ++l) SA(0, 0, l);
#pragma unroll
  for (int l = 0; l < 3; ++l) SB(0, 0, l);
#pragma unroll
  for (int l = 0; l < 4; ++l) SA(1, 1, l);
#pragma unroll
  for (int l = 0; l < 3; ++l) SB(1, 1, l);
  asm volatile("s_waitcnt vmcnt(7)" ::: "memory");   // tile 0 landed
  __builtin_amdgcn_s_barrier();
  __builtin_amdgcn_sched_barrier(0);
#pragma unroll
  for (int m4 = 0; m4 < 8; ++m4) aA[m4] = *(const bf16x8*)&Asb[0][aO0 + m4 * 1024];
#pragma unroll
  for (int n = 0; n < 3; ++n) bA[n] = *(const bf16x8*)&Bsb[0][bO0 + n * 1024];

  for (int t = 0; t < nt; ++t) {
    const int cur = t & 1;
    const __bf16* Asc = Asb[cur];
    const __bf16* Bsc = Bsb[cur];
    const __bf16* Asn = Asb[cur ^ 1];
    const __bf16* Bsn = Bsb[cur ^ 1];
    // 1. reads kk1 of tile t (cur buf) -> set B   [11 ds_read_b128, fly under step 2]
#pragma unroll
    for (int m4 = 0; m4 < 8; ++m4) aB[m4] = *(const bf16x8*)&Asc[aO1 + m4 * 1024];
#pragma unroll
    for (int n = 0; n < 3; ++n) bB[n] = *(const bf16x8*)&Bsc[bO1 + n * 1024];
    // 2. MFMA kk0 (set A; read one iteration ago -> no wait)
    __builtin_amdgcn_s_setprio(1);
#pragma unroll
    for (int m = 0; m < 8; ++m)
#pragma unroll
      for (int n = 0; n < 3; ++n) acc[m][n] = mfma16(aA[m], bA[n], acc[m][n]);
    __builtin_amdgcn_s_setprio(0);
    // 3. stage(t+1 -> nxt buf) landed everywhere
    asm volatile("s_waitcnt vmcnt(0)" ::: "memory");
    __builtin_amdgcn_s_barrier();
    __builtin_amdgcn_sched_barrier(0);
    // 4. reads kk0 of tile t+1 (nxt buf) -> set A
#pragma unroll
    for (int m4 = 0; m4 < 8; ++m4) aA[m4] = *(const bf16x8*)&Asn[aO0 + m4 * 1024];
#pragma unroll
    for (int n = 0; n < 3; ++n) bA[n] = *(const bf16x8*)&Bsn[bO0 + n * 1024];
    __builtin_amdgcn_sched_barrier(0);
    // 5. certify step-1 reads complete (leave the 11 step-4 reads in flight), then BAR2
    asm volatile("s_waitcnt lgkmcnt(11)" ::: "memory");
    __builtin_amdgcn_sched_barrier(0);
    __builtin_amdgcn_s_barrier();
    __builtin_amdgcn_sched_barrier(0);
    // 6. stage tile t+2 -> cur buf (drains at next iteration's step 3)
    {
      int ts = (t + 2 < nt) ? t + 2 : t + 2 - nt;   // dummy wrap on tail
#pragma unroll
      for (int l = 0; l < 4; ++l) SA(cur, ts, l);
#pragma unroll
      for (int l = 0; l < 3; ++l) SB(cur, ts, l);
    }
    // 7. MFMA kk1 (set B; certified at step 5 -> no wait)
    __builtin_amdgcn_s_setprio(1);
#pragma unroll
    for (int m = 0; m < 8; ++m)
#pragma unroll
      for (int n = 0; n < 3; ++n) acc[m][n] = mfma16(aB[m], bB[n], acc[m][n]);
    __builtin_amdgcn_s_setprio(0);
  }
#undef SA
#undef SB

#pragma unroll
  for (int m = 0; m < 8; ++m)
#pragma unroll
    for (int n = 0; n < 3; ++n) {
      int col = n0 + wn * 48 + n * 16 + lr;
      float bc = bias[col];
#pragma unroll
      for (int j = 0; j < 4; ++j) {
        int row = m0 + wm * 128 + m * 16 + lh * 4 + j;
        float v = acc[m][n][j] + bc;
        if (EPI == 1) v = gelu_f(v);
        if (EPI == 2) outf[(long)row * N + col] = v + res[(long)row * N + col];
        else          outb[(long)row * N + col] = (__bf16)v;
      }
    }
}

// ---- flash attention on fused qkv buffer (rows x 2304). (unchanged from R6/R7)
__global__ __launch_bounds__(256) void attn_kernel(const __bf16* __restrict__ qkv, __bf16* __restrict__ o) {
  __shared__ __bf16 K_lds[64][72];
  __shared__ __align__(16) unsigned char Vt[8448];
  __shared__ __bf16 P_lds[4][32][72];
  const int tid = threadIdx.x;
  const int lane = tid & 63, wv = tid >> 6;
  const int lr = lane & 15, lh = lane >> 4;
  const int hb = blockIdx.x, qt = blockIdx.y;
  const int h = hb % 12, bz = hb / 12;
  const int qrow0 = bz * 1024 + qt * 128 + wv * 32;
  const int hcol = h * 64;
  const __bf16* q = qkv + hcol;
  const __bf16* k = qkv + 768 + hcol;
  const __bf16* v = qkv + 1536 + hcol;
  const float QSC = 0.18033688011112042f;  // 0.125 * log2(e)
  bf16x8 aq[2][2];
#pragma unroll
  for (int r = 0; r < 2; ++r)
#pragma unroll
    for (int kk = 0; kk < 2; ++kk) {
      bf16x8 t = *(const bf16x8*)(q + (long)(qrow0 + r * 16 + lr) * 2304 + kk * 32 + lh * 8);
#pragma unroll
      for (int e = 0; e < 8; ++e) t[e] = (__bf16)((float)t[e] * QSC);
      aq[r][kk] = t;
    }
  bf16x8 ones;
#pragma unroll
  for (int e = 0; e < 8; ++e) ones[e] = (__bf16)1.0f;
  f32x4 o_fr[2][4] = {};
  float m_s[2][4], l_s[2][4];
#pragma unroll
  for (int r = 0; r < 2; ++r)
#pragma unroll
    for (int j = 0; j < 4; ++j) { m_s[r][j] = 0.0f; l_s[r][j] = 0.0f; }
  const int r0 = tid >> 3, c0 = (tid & 7) * 8;
  const unsigned vt0 = lds_off(Vt) + (lane >> 4) * 1056 + (lane & 15) * 2;
  const int Tst = (r0 >> 2) * 4 + (c0 >> 4);
  const int vb = Tst * 128 + (r0 & 3) * 32 + (c0 & 15) * 2 + (Tst >> 3) * 32;

  bf16x8 rK[2], rV[2];
#pragma unroll
  for (int p = 0; p < 2; ++p) {
    long gr = (long)(bz * 1024 + p * 32 + r0) * 2304 + c0;
    rK[p] = *(const bf16x8*)(k + gr);
    rV[p] = *(const bf16x8*)(v + gr);
  }
#pragma unroll
  for (int p = 0; p < 2; ++p) {
    *(bf16x8*)&K_lds[p * 32 + r0][c0] = rK[p];
    *(bf16x8*)(Vt + vb + p * 4224) = rV[p];
  }
  __syncthreads();

  for (int t = 0; t < 16; ++t) {
    bf16x8 bk[4][2];
#pragma unroll
    for (int n = 0; n < 4; ++n)
#pragma unroll
      for (int kk = 0; kk < 2; ++kk)
        bk[n][kk] = *(const bf16x8*)&K_lds[n * 16 + lr][kk * 32 + lh * 8];
    if (t < 15) {
#pragma unroll
      for (int p = 0; p < 2; ++p) {
        long gr = (long)(bz * 1024 + (t + 1) * 64 + p * 32 + r0) * 2304 + c0;
        rK[p] = *(const bf16x8*)(k + gr);
        rV[p] = *(const bf16x8*)(v + gr);
      }
    }
    f32x4 sf[2][4];
    __builtin_amdgcn_s_setprio(1);
#pragma unroll
    for (int r = 0; r < 2; ++r)
#pragma unroll
      for (int n = 0; n < 4; ++n) {
        f32x4 s = {0.f, 0.f, 0.f, 0.f};
        s = mfma16(aq[r][0], bk[n][0], s);
        s = mfma16(aq[r][1], bk[n][1], s);
        sf[r][n] = s;
      }
    __builtin_amdgcn_s_setprio(0);
    float pp[2][4][4];
    bool ok = true;
#pragma unroll
    for (int r = 0; r < 2; ++r)
#pragma unroll
      for (int j = 0; j < 4; ++j) {
        float lm = fmaxf(fmaxf(sf[r][0][j], sf[r][1][j]), fmaxf(sf[r][2][j], sf[r][3][j]));
        ok = ok && (lm <= m_s[r][j] + 11.54f);
      }
    if (!__all(ok)) {
#pragma unroll
      for (int r = 0; r < 2; ++r) {
        float rmax[4];
#pragma unroll
        for (int j = 0; j < 4; ++j)
          rmax[j] = fmaxf(fmaxf(sf[r][0][j], sf[r][1][j]), fmaxf(sf[r][2][j], sf[r][3][j]));
#pragma unroll
        for (int m = 1; m < 16; m <<= 1)
#pragma unroll
          for (int j = 0; j < 4; ++j) rmax[j] = fmaxf(rmax[j], __shfl_xor(rmax[j], m));
#pragma unroll
        for (int j = 0; j < 4; ++j) {
          float nm = fmaxf(m_s[r][j], rmax[j]);
          float corr = __builtin_amdgcn_exp2f(m_s[r][j] - nm);
          m_s[r][j] = nm;
          l_s[r][j] *= corr;
#pragma unroll
          for (int d = 0; d < 4; ++d) o_fr[r][d][j] *= corr;
        }
      }
    }
#pragma unroll
    for (int r = 0; r < 2; ++r)
#pragma unroll
      for (int n = 0; n < 4; ++n)
#pragma unroll
        for (int j = 0; j < 4; ++j)
          pp[r][n][j] = __builtin_amdgcn_exp2f(sf[r][n][j] - m_s[r][j]);
#pragma unroll
    for (int r = 0; r < 2; ++r)
#pragma unroll
      for (int n = 0; n < 4; ++n)
#pragma unroll
        for (int j = 0; j < 4; ++j)
          P_lds[wv][r * 16 + lh * 4 + j][n * 16 + lr] = (__bf16)pp[r][n][j];
    u32x2 trv[4][2][2];
#pragma unroll
    for (int d0 = 0; d0 < 4; ++d0)
#pragma unroll
      for (int ks = 0; ks < 2; ++ks) {
        unsigned a = vt0 + ks * 4224 + d0 * 128;
        asm volatile("ds_read_b64_tr_b16 %0, %1" : "=v"(trv[d0][ks][0]) : "v"(a));
        asm volatile("ds_read_b64_tr_b16 %0, %1 offset:512" : "=v"(trv[d0][ks][1]) : "v"(a));
      }
    bf16x8 ap[2][2];
#pragma unroll
    for (int r = 0; r < 2; ++r)
#pragma unroll
      for (int ks = 0; ks < 2; ++ks)
        ap[r][ks] = *(const bf16x8*)&P_lds[wv][r * 16 + lr][ks * 32 + lh * 8];
    asm volatile("s_waitcnt lgkmcnt(0)");
    __builtin_amdgcn_sched_barrier(0);
    __builtin_amdgcn_s_setprio(1);
#pragma unroll
    for (int r = 0; r < 2; ++r) {
      f32x4 ls = {0.f, 0.f, 0.f, 0.f};
      ls = mfma16(ap[r][0], ones, ls);
      ls = mfma16(ap[r][1], ones, ls);
#pragma unroll
      for (int j = 0; j < 4; ++j) l_s[r][j] += ls[j];
    }
#pragma unroll
    for (int d0 = 0; d0 < 4; ++d0) {
      union { u32x2 u[2]; bf16x8 v8; } b0, b1;
      b0.u[0] = trv[d0][0][0]; b0.u[1] = trv[d0][0][1];
      b1.u[0] = trv[d0][1][0]; b1.u[1] = trv[d0][1][1];
#pragma unroll
      for (int r = 0; r < 2; ++r) {
        o_fr[r][d0] = mfma16(ap[r][0], b0.v8, o_fr[r][d0]);
        o_fr[r][d0] = mfma16(ap[r][1], b1.v8, o_fr[r][d0]);
      }
    }
    __builtin_amdgcn_s_setprio(0);
    __syncthreads();
    if (t < 15) {
#pragma unroll
      for (int p = 0; p < 2; ++p) {
        *(bf16x8*)&K_lds[p * 32 + r0][c0] = rK[p];
        *(bf16x8*)(Vt + vb + p * 4224) = rV[p];
      }
      __syncthreads();
    }
  }
#pragma unroll
  for (int r = 0; r < 2; ++r)
#pragma unroll
    for (int d = 0; d < 4; ++d)
#pragma unroll
      for (int j = 0; j < 4; ++j) {
        int row = qrow0 + r * 16 + lh * 4 + j;
        int col = hcol + d * 16 + lr;
        o[(long)row * 768 + col] = (__bf16)(o_fr[r][d][j] * (1.0f / l_s[r][j]));
      }
}

extern "C" void kernel_launch(void* const* d_in, const int* in_sizes, int n_in,
                              void* d_out, int out_size, void* d_ws, size_t ws_size,
                              hipStream_t stream) {
  const float* x    = (const float*)d_in[0];
  const float* ln1g = (const float*)d_in[1];
  const float* ln1b = (const float*)d_in[2];
  const float* wq   = (const float*)d_in[3];
  const float* bq   = (const float*)d_in[4];
  const float* wk   = (const float*)d_in[5];
  const float* bk   = (const float*)d_in[6];
  const float* wv   = (const float*)d_in[7];
  const float* bv   = (const float*)d_in[8];
  const float* wo   = (const float*)d_in[9];
  const float* bo   = (const float*)d_in[10];
  const float* ln2g = (const float*)d_in[11];
  const float* ln2b = (const float*)d_in[12];
  const float* w1   = (const float*)d_in[13];
  const float* b1   = (const float*)d_in[14];
  const float* w2   = (const float*)d_in[15];
  const float* b2   = (const float*)d_in[16];
  float* out = (float*)d_out;
  char* ws = (char*)d_ws;

  const long SD = 16384L * 768;
  const long SF = 16384L * 3072;

  __bf16* qkv = (__bf16*)(ws);                      // 16384 x 2304
  __bf16* f1  = (__bf16*)(ws);                      // aliases qkv (dead by FFN1)
  __bf16* hb  = (__bf16*)(ws + 2 * SF);             // LN1 out; later attn out
  float*  x2  = (float*)(ws + 2 * SF + 2 * SD);
  __bf16* h2  = (__bf16*)(ws + 2 * SF + 2 * SD + 4 * SD);
  __bf16* wtqkv = (__bf16*)(ws + 2 * SF + 2 * SD + 4 * SD + 2 * SD);  // 2304 x 768
  __bf16* wto = wtqkv + 2304L * 768;
  __bf16* wt1 = wto + 768L * 768;
  __bf16* wt2 = wt1 + 768L * 3072;
  float*  bqkv = (float*)(wt2 + 3072L * 768);

  wprep_qkv_kernel<<<(2304 * 768 + 255) / 256, 256, 0, stream>>>(wq, wk, wv, wtqkv);
  wprep_kernel<<<(768 * 768 + 255) / 256, 256, 0, stream>>>(wo, wto, 768, 768);
  wprep_kernel<<<(768 * 3072 + 255) / 256, 256, 0, stream>>>(w1, wt1, 768, 3072);
  wprep_kernel<<<(768 * 3072 + 255) / 256, 256, 0, stream>>>(w2, wt2, 3072, 768);
  bias_cat_kernel<<<9, 256, 0, stream>>>(bq, bk, bv, bqkv);

  ln_kernel<<<16384, 256, 0, stream>>>(x, ln1g, ln1b, hb);
  gemm_kernel<0><<<dim3(12, 64), 512, 0, stream>>>(hb, wtqkv, bqkv, nullptr, nullptr, qkv, 16384, 2304, 768);
  attn_kernel<<<dim3(192, 8), 256, 0, stream>>>(qkv, hb);
  gemm_kernel<2><<<dim3(4, 64), 512, 0, stream>>>(hb, wto, bo, x, x2, nullptr, 16384, 768, 768);
  ln_kernel<<<16384, 256, 0, stream>>>(x2, ln2g, ln2b, h2);
  gemm_kernel<1><<<dim3(16, 64), 512, 0, stream>>>(h2, wt1, b1, nullptr, nullptr, f1, 16384, 3072, 768);
  gemm_kernel<2><<<dim3(4, 64), 512, 0, stream>>>(f1, wt2, b2, x2, out, nullptr, 16384, 768, 3072);
}

// Round 9
// 434.724 us; speedup vs baseline: 1.3700x; 1.2205x over previous
//
#include <hip/hip_runtime.h>
#include <hip/hip_bf16.h>
#include <math.h>

typedef __bf16 bf16x8 __attribute__((ext_vector_type(8)));
typedef __bf16 bf16x4 __attribute__((ext_vector_type(4)));
typedef float f32x4 __attribute__((ext_vector_type(4)));
typedef unsigned int u32x2 __attribute__((ext_vector_type(2)));

__device__ __forceinline__ f32x4 mfma16(bf16x8 a, bf16x8 b, f32x4 c) {
  return __builtin_amdgcn_mfma_f32_16x16x32_bf16(a, b, c, 0, 0, 0);
}

__device__ __forceinline__ float gelu_f(float v) {
  return 0.5f * v * (1.0f + erff(v * 0.70710678118654752f));
}

__device__ __forceinline__ void async16(const void* g, void* l) {
  __builtin_amdgcn_global_load_lds((const __attribute__((address_space(1))) unsigned int*)g,
                                   (__attribute__((address_space(3))) unsigned int*)l, 16, 0, 0);
}

__device__ __forceinline__ unsigned lds_off(const void* p) {
  return (unsigned)(unsigned long long)(const __attribute__((address_space(3))) void*)p;
}

// ---- tiled transpose + bf16 convert: Wt[n][k] = (bf16) W[k][n];  W is K x N row-major.
// 64x64 tiles via LDS; coalesced float4 reads, 8B bf16 writes. grid (N/64, K/64).
__global__ __launch_bounds__(256) void wprep_kernel(const float* __restrict__ W, __bf16* __restrict__ Wt,
                                                    int K, int N) {
  __shared__ __bf16 tile[64][65];
  const int tn0 = blockIdx.x * 64, tk0 = blockIdx.y * 64;
  const int tr = threadIdx.x >> 4, tc = (threadIdx.x & 15) * 4;
#pragma unroll
  for (int p = 0; p < 4; ++p) {
    int r = p * 16 + tr;
    float4 v = *(const float4*)&W[(long)(tk0 + r) * N + tn0 + tc];
    tile[tc + 0][r] = (__bf16)v.x;
    tile[tc + 1][r] = (__bf16)v.y;
    tile[tc + 2][r] = (__bf16)v.z;
    tile[tc + 3][r] = (__bf16)v.w;
  }
  __syncthreads();
#pragma unroll
  for (int p = 0; p < 4; ++p) {
    int n = p * 16 + tr;
    bf16x4 o;
    o[0] = tile[n][tc]; o[1] = tile[n][tc + 1]; o[2] = tile[n][tc + 2]; o[3] = tile[n][tc + 3];
    *(bf16x4*)&Wt[(long)(tn0 + n) * K + tk0 + tc] = o;
  }
}

__global__ void bias_cat_kernel(const float* __restrict__ bq, const float* __restrict__ bk,
                                const float* __restrict__ bv, float* __restrict__ o) {
  int i = blockIdx.x * 256 + threadIdx.x;
  if (i >= 2304) return;
  o[i] = (i < 768) ? bq[i] : (i < 1536) ? bk[i - 768] : bv[i - 1536];
}

// ---- layernorm: fp32 in (rows x 768), bf16 out. One block (256 thr) per row.
__global__ __launch_bounds__(256) void ln_kernel(const float* __restrict__ x, const float* __restrict__ g,
                                                 const float* __restrict__ b, __bf16* __restrict__ out) {
  int row = blockIdx.x;
  const float* xr = x + (long)row * 768;
  float v0 = xr[threadIdx.x], v1 = xr[threadIdx.x + 256], v2 = xr[threadIdx.x + 512];
  float s = v0 + v1 + v2, s2 = v0 * v0 + v1 * v1 + v2 * v2;
#pragma unroll
  for (int m = 1; m < 64; m <<= 1) { s += __shfl_xor(s, m); s2 += __shfl_xor(s2, m); }
  __shared__ float ws1[4], ws2[4];
  int wv = threadIdx.x >> 6;
  if ((threadIdx.x & 63) == 0) { ws1[wv] = s; ws2[wv] = s2; }
  __syncthreads();
  s = ws1[0] + ws1[1] + ws1[2] + ws1[3];
  s2 = ws2[0] + ws2[1] + ws2[2] + ws2[3];
  float mu = s * (1.0f / 768.0f);
  float var = s2 * (1.0f / 768.0f) - mu * mu;
  float rstd = rsqrtf(var + 1e-5f);
  __bf16* orow = out + (long)row * 768;
  orow[threadIdx.x]       = (__bf16)((v0 - mu) * rstd * g[threadIdx.x]       + b[threadIdx.x]);
  orow[threadIdx.x + 256] = (__bf16)((v1 - mu) * rstd * g[threadIdx.x + 256] + b[threadIdx.x + 256]);
  orow[threadIdx.x + 512] = (__bf16)((v2 - mu) * rstd * g[threadIdx.x + 512] + b[threadIdx.x + 512]);
}

// ---- GEMM: m103-validated structure. 128x128 tile, BK=64, 256 thr (4 waves, wave tile 64x64),
// single-buffer 32KB LDS, 2-phase __syncthreads loop, global_load_lds w16, T2 xor-swizzle,
// bijective XCD swizzle. 3 blocks/CU co-resident (launch_bounds 256,3) provide the overlap.
// C[M,N] = epi(A[M,K] @ Wt[N,K]^T + bias). M%128==0, N%128==0, K%64==0, gridDim.y%8==0.
template <int EPI>
__global__ __launch_bounds__(256, 3) void gemm_kernel(const __bf16* __restrict__ A, const __bf16* __restrict__ Wt,
                                                      const float* __restrict__ bias, const float* __restrict__ res,
                                                      float* __restrict__ outf, __bf16* __restrict__ outb,
                                                      int M, int N, int K) {
  __shared__ __align__(16) __bf16 As[8192];   // 128 x 64
  __shared__ __align__(16) __bf16 Bs[8192];   // 128 x 64
  const int tid = threadIdx.x, lane = tid & 63, w = tid >> 6;
  const int wm = w >> 1, wn = w & 1, lr = lane & 15, lh = lane >> 4;
  // bijective XCD swizzle: consecutive m-panels per XCD (gridDim.y % 8 == 0)
  const int gx = gridDim.x, gy = gridDim.y;
  int id = blockIdx.x + gx * blockIdx.y;
  int xcd = id & 7, slot = id >> 3;
  int by = xcd * (gy >> 3) + slot / gx;
  int bx = slot % gx;
  const int m0 = by * 128, n0 = bx * 128;
  const int nt = K >> 6;
  int srow[4], scol[4];
#pragma unroll
  for (int l = 0; l < 4; ++l) {
    int c = l * 256 + tid;
    srow[l] = c >> 3;
    scol[l] = ((c & 7) ^ ((c >> 3) & 7)) * 8;
  }
  const __bf16* Ag = A + (long)m0 * K;
  const __bf16* Bg = Wt + (long)n0 * K;

  f32x4 acc[4][4] = {};
  for (int t = 0; t < nt; ++t) {
    const int kb = t << 6;
    __syncthreads();
#pragma unroll
    for (int l = 0; l < 4; ++l) {
      async16(Ag + (long)srow[l] * K + kb + scol[l], &As[l * 2048 + w * 512]);
      async16(Bg + (long)srow[l] * K + kb + scol[l], &Bs[l * 2048 + w * 512]);
    }
    __syncthreads();
    bf16x8 af[4][2], bfr[4][2];
#pragma unroll
    for (int m4 = 0; m4 < 4; ++m4) {
      int row = wm * 64 + m4 * 16 + lr;
#pragma unroll
      for (int kk = 0; kk < 2; ++kk)
        af[m4][kk] = *(const bf16x8*)&As[row * 64 + ((kk * 32 + lh * 8) ^ ((row & 7) << 3))];
    }
#pragma unroll
    for (int n = 0; n < 4; ++n) {
      int row = wn * 64 + n * 16 + lr;
#pragma unroll
      for (int kk = 0; kk < 2; ++kk)
        bfr[n][kk] = *(const bf16x8*)&Bs[row * 64 + ((kk * 32 + lh * 8) ^ ((row & 7) << 3))];
    }
    __builtin_amdgcn_s_setprio(1);
#pragma unroll
    for (int m4 = 0; m4 < 4; ++m4)
#pragma unroll
      for (int n = 0; n < 4; ++n) {
        acc[m4][n] = mfma16(af[m4][0], bfr[n][0], acc[m4][n]);
        acc[m4][n] = mfma16(af[m4][1], bfr[n][1], acc[m4][n]);
      }
    __builtin_amdgcn_s_setprio(0);
  }

#pragma unroll
  for (int m = 0; m < 4; ++m)
#pragma unroll
    for (int n = 0; n < 4; ++n) {
      int col = n0 + wn * 64 + n * 16 + lr;
      float bc = bias[col];
#pragma unroll
      for (int j = 0; j < 4; ++j) {
        int row = m0 + wm * 64 + m * 16 + lh * 4 + j;
        float v = acc[m][n][j] + bc;
        if (EPI == 1) v = gelu_f(v);
        if (EPI == 2) outf[(long)row * N + col] = v + res[(long)row * N + col];
        else          outb[(long)row * N + col] = (__bf16)v;
      }
    }
}

// ---- flash attention on fused qkv buffer (rows x 2304). (unchanged from R8)
__global__ __launch_bounds__(256) void attn_kernel(const __bf16* __restrict__ qkv, __bf16* __restrict__ o) {
  __shared__ __bf16 K_lds[64][72];
  __shared__ __align__(16) unsigned char Vt[8448];
  __shared__ __bf16 P_lds[4][32][72];
  const int tid = threadIdx.x;
  const int lane = tid & 63, wv = tid >> 6;
  const int lr = lane & 15, lh = lane >> 4;
  const int hb = blockIdx.x, qt = blockIdx.y;
  const int h = hb % 12, bz = hb / 12;
  const int qrow0 = bz * 1024 + qt * 128 + wv * 32;
  const int hcol = h * 64;
  const __bf16* q = qkv + hcol;
  const __bf16* k = qkv + 768 + hcol;
  const __bf16* v = qkv + 1536 + hcol;
  const float QSC = 0.18033688011112042f;  // 0.125 * log2(e)
  bf16x8 aq[2][2];
#pragma unroll
  for (int r = 0; r < 2; ++r)
#pragma unroll
    for (int kk = 0; kk < 2; ++kk) {
      bf16x8 t = *(const bf16x8*)(q + (long)(qrow0 + r * 16 + lr) * 2304 + kk * 32 + lh * 8);
#pragma unroll
      for (int e = 0; e < 8; ++e) t[e] = (__bf16)((float)t[e] * QSC);
      aq[r][kk] = t;
    }
  bf16x8 ones;
#pragma unroll
  for (int e = 0; e < 8; ++e) ones[e] = (__bf16)1.0f;
  f32x4 o_fr[2][4] = {};
  float m_s[2][4], l_s[2][4];
#pragma unroll
  for (int r = 0; r < 2; ++r)
#pragma unroll
    for (int j = 0; j < 4; ++j) { m_s[r][j] = 0.0f; l_s[r][j] = 0.0f; }
  const int r0 = tid >> 3, c0 = (tid & 7) * 8;
  const unsigned vt0 = lds_off(Vt) + (lane >> 4) * 1056 + (lane & 15) * 2;
  const int Tst = (r0 >> 2) * 4 + (c0 >> 4);
  const int vb = Tst * 128 + (r0 & 3) * 32 + (c0 & 15) * 2 + (Tst >> 3) * 32;

  bf16x8 rK[2], rV[2];
#pragma unroll
  for (int p = 0; p < 2; ++p) {
    long gr = (long)(bz * 1024 + p * 32 + r0) * 2304 + c0;
    rK[p] = *(const bf16x8*)(k + gr);
    rV[p] = *(const bf16x8*)(v + gr);
  }
#pragma unroll
  for (int p = 0; p < 2; ++p) {
    *(bf16x8*)&K_lds[p * 32 + r0][c0] = rK[p];
    *(bf16x8*)(Vt + vb + p * 4224) = rV[p];
  }
  __syncthreads();

  for (int t = 0; t < 16; ++t) {
    bf16x8 bk[4][2];
#pragma unroll
    for (int n = 0; n < 4; ++n)
#pragma unroll
      for (int kk = 0; kk < 2; ++kk)
        bk[n][kk] = *(const bf16x8*)&K_lds[n * 16 + lr][kk * 32 + lh * 8];
    if (t < 15) {
#pragma unroll
      for (int p = 0; p < 2; ++p) {
        long gr = (long)(bz * 1024 + (t + 1) * 64 + p * 32 + r0) * 2304 + c0;
        rK[p] = *(const bf16x8*)(k + gr);
        rV[p] = *(const bf16x8*)(v + gr);
      }
    }
    f32x4 sf[2][4];
    __builtin_amdgcn_s_setprio(1);
#pragma unroll
    for (int r = 0; r < 2; ++r)
#pragma unroll
      for (int n = 0; n < 4; ++n) {
        f32x4 s = {0.f, 0.f, 0.f, 0.f};
        s = mfma16(aq[r][0], bk[n][0], s);
        s = mfma16(aq[r][1], bk[n][1], s);
        sf[r][n] = s;
      }
    __builtin_amdgcn_s_setprio(0);
    float pp[2][4][4];
    bool ok = true;
#pragma unroll
    for (int r = 0; r < 2; ++r)
#pragma unroll
      for (int j = 0; j < 4; ++j) {
        float lm = fmaxf(fmaxf(sf[r][0][j], sf[r][1][j]), fmaxf(sf[r][2][j], sf[r][3][j]));
        ok = ok && (lm <= m_s[r][j] + 11.54f);
      }
    if (!__all(ok)) {
#pragma unroll
      for (int r = 0; r < 2; ++r) {
        float rmax[4];
#pragma unroll
        for (int j = 0; j < 4; ++j)
          rmax[j] = fmaxf(fmaxf(sf[r][0][j], sf[r][1][j]), fmaxf(sf[r][2][j], sf[r][3][j]));
#pragma unroll
        for (int m = 1; m < 16; m <<= 1)
#pragma unroll
          for (int j = 0; j < 4; ++j) rmax[j] = fmaxf(rmax[j], __shfl_xor(rmax[j], m));
#pragma unroll
        for (int j = 0; j < 4; ++j) {
          float nm = fmaxf(m_s[r][j], rmax[j]);
          float corr = __builtin_amdgcn_exp2f(m_s[r][j] - nm);
          m_s[r][j] = nm;
          l_s[r][j] *= corr;
#pragma unroll
          for (int d = 0; d < 4; ++d) o_fr[r][d][j] *= corr;
        }
      }
    }
#pragma unroll
    for (int r = 0; r < 2; ++r)
#pragma unroll
      for (int n = 0; n < 4; ++n)
#pragma unroll
        for (int j = 0; j < 4; ++j)
          pp[r][n][j] = __builtin_amdgcn_exp2f(sf[r][n][j] - m_s[r][j]);
#pragma unroll
    for (int r = 0; r < 2; ++r)
#pragma unroll
      for (int n = 0; n < 4; ++n)
#pragma unroll
        for (int j = 0; j < 4; ++j)
          P_lds[wv][r * 16 + lh * 4 + j][n * 16 + lr] = (__bf16)pp[r][n][j];
    u32x2 trv[4][2][2];
#pragma unroll
    for (int d0 = 0; d0 < 4; ++d0)
#pragma unroll
      for (int ks = 0; ks < 2; ++ks) {
        unsigned a = vt0 + ks * 4224 + d0 * 128;
        asm volatile("ds_read_b64_tr_b16 %0, %1" : "=v"(trv[d0][ks][0]) : "v"(a));
        asm volatile("ds_read_b64_tr_b16 %0, %1 offset:512" : "=v"(trv[d0][ks][1]) : "v"(a));
      }
    bf16x8 ap[2][2];
#pragma unroll
    for (int r = 0; r < 2; ++r)
#pragma unroll
      for (int ks = 0; ks < 2; ++ks)
        ap[r][ks] = *(const bf16x8*)&P_lds[wv][r * 16 + lr][ks * 32 + lh * 8];
    asm volatile("s_waitcnt lgkmcnt(0)");
    __builtin_amdgcn_sched_barrier(0);
    __builtin_amdgcn_s_setprio(1);
#pragma unroll
    for (int r = 0; r < 2; ++r) {
      f32x4 ls = {0.f, 0.f, 0.f, 0.f};
      ls = mfma16(ap[r][0], ones, ls);
      ls = mfma16(ap[r][1], ones, ls);
#pragma unroll
      for (int j = 0; j < 4; ++j) l_s[r][j] += ls[j];
    }
#pragma unroll
    for (int d0 = 0; d0 < 4; ++d0) {
      union { u32x2 u[2]; bf16x8 v8; } b0, b1;
      b0.u[0] = trv[d0][0][0]; b0.u[1] = trv[d0][0][1];
      b1.u[0] = trv[d0][1][0]; b1.u[1] = trv[d0][1][1];
#pragma unroll
      for (int r = 0; r < 2; ++r) {
        o_fr[r][d0] = mfma16(ap[r][0], b0.v8, o_fr[r][d0]);
        o_fr[r][d0] = mfma16(ap[r][1], b1.v8, o_fr[r][d0]);
      }
    }
    __builtin_amdgcn_s_setprio(0);
    __syncthreads();
    if (t < 15) {
#pragma unroll
      for (int p = 0; p < 2; ++p) {
        *(bf16x8*)&K_lds[p * 32 + r0][c0] = rK[p];
        *(bf16x8*)(Vt + vb + p * 4224) = rV[p];
      }
      __syncthreads();
    }
  }
#pragma unroll
  for (int r = 0; r < 2; ++r)
#pragma unroll
    for (int d = 0; d < 4; ++d)
#pragma unroll
      for (int j = 0; j < 4; ++j) {
        int row = qrow0 + r * 16 + lh * 4 + j;
        int col = hcol + d * 16 + lr;
        o[(long)row * 768 + col] = (__bf16)(o_fr[r][d][j] * (1.0f / l_s[r][j]));
      }
}

extern "C" void kernel_launch(void* const* d_in, const int* in_sizes, int n_in,
                              void* d_out, int out_size, void* d_ws, size_t ws_size,
                              hipStream_t stream) {
  const float* x    = (const float*)d_in[0];
  const float* ln1g = (const float*)d_in[1];
  const float* ln1b = (const float*)d_in[2];
  const float* wq   = (const float*)d_in[3];
  const float* bq   = (const float*)d_in[4];
  const float* wk   = (const float*)d_in[5];
  const float* bk   = (const float*)d_in[6];
  const float* wv   = (const float*)d_in[7];
  const float* bv   = (const float*)d_in[8];
  const float* wo   = (const float*)d_in[9];
  const float* bo   = (const float*)d_in[10];
  const float* ln2g = (const float*)d_in[11];
  const float* ln2b = (const float*)d_in[12];
  const float* w1   = (const float*)d_in[13];
  const float* b1   = (const float*)d_in[14];
  const float* w2   = (const float*)d_in[15];
  const float* b2   = (const float*)d_in[16];
  float* out = (float*)d_out;
  char* ws = (char*)d_ws;

  const long SD = 16384L * 768;
  const long SF = 16384L * 3072;

  __bf16* qkv = (__bf16*)(ws);                      // 16384 x 2304
  __bf16* f1  = (__bf16*)(ws);                      // aliases qkv (dead by FFN1)
  __bf16* hb  = (__bf16*)(ws + 2 * SF);             // LN1 out; later attn out
  float*  x2  = (float*)(ws + 2 * SF + 2 * SD);
  __bf16* h2  = (__bf16*)(ws + 2 * SF + 2 * SD + 4 * SD);
  __bf16* wtqkv = (__bf16*)(ws + 2 * SF + 2 * SD + 4 * SD + 2 * SD);  // 2304 x 768
  __bf16* wto = wtqkv + 2304L * 768;
  __bf16* wt1 = wto + 768L * 768;
  __bf16* wt2 = wt1 + 768L * 3072;
  float*  bqkv = (float*)(wt2 + 3072L * 768);

  // weight prep: tiled transpose (grid = (N/64, K/64))
  wprep_kernel<<<dim3(12, 12), 256, 0, stream>>>(wq, wtqkv,               768, 768);
  wprep_kernel<<<dim3(12, 12), 256, 0, stream>>>(wk, wtqkv + 768L * 768,  768, 768);
  wprep_kernel<<<dim3(12, 12), 256, 0, stream>>>(wv, wtqkv + 1536L * 768, 768, 768);
  wprep_kernel<<<dim3(12, 12), 256, 0, stream>>>(wo, wto, 768, 768);
  wprep_kernel<<<dim3(48, 12), 256, 0, stream>>>(w1, wt1, 768, 3072);
  wprep_kernel<<<dim3(12, 48), 256, 0, stream>>>(w2, wt2, 3072, 768);
  bias_cat_kernel<<<9, 256, 0, stream>>>(bq, bk, bv, bqkv);

  ln_kernel<<<16384, 256, 0, stream>>>(x, ln1g, ln1b, hb);
  gemm_kernel<0><<<dim3(18, 128), 256, 0, stream>>>(hb, wtqkv, bqkv, nullptr, nullptr, qkv, 16384, 2304, 768);
  attn_kernel<<<dim3(192, 8), 256, 0, stream>>>(qkv, hb);
  gemm_kernel<2><<<dim3(6, 128), 256, 0, stream>>>(hb, wto, bo, x, x2, nullptr, 16384, 768, 768);
  ln_kernel<<<16384, 256, 0, stream>>>(x2, ln2g, ln2b, h2);
  gemm_kernel<1><<<dim3(24, 128), 256, 0, stream>>>(h2, wt1, b1, nullptr, nullptr, f1, 16384, 3072, 768);
  gemm_kernel<2><<<dim3(6, 128), 256, 0, stream>>>(f1, wt2, b2, x2, out, nullptr, 16384, 768, 3072);
}